// Round 5
// baseline (1401.676 us; speedup 1.0000x reference)
//
#include <hip/hip_runtime.h>

// Problem constants (from reference): 16 clouds x 4096 pts, sample 1024, D=512
#define N_PER   4096
#define M_SAMP  1024
#define B_CL    16
#define D_FEAT  512
#define TPB     512
#define NWAVE   (TPB / 64)      // 8 waves
#define PPT     (N_PER / TPB)   // 8 points per thread (thread t owns t*8..t*8+7)

// ---------------------------------------------------------------------------
// DPP 5-tuple argmax combine: key u64 desc, carrying winner coords (x,y,z).
// key = (float_bits(val) << 32) | (4095 - idx):
//   max key == max val; tie -> min idx  (exact jnp.argmax first-occurrence)
// Lanes not supplied by the DPP pattern combine with themselves (no-op).
// ---------------------------------------------------------------------------
template <int CTRL>
__device__ __forceinline__ void dpp_combine5(unsigned& khi, unsigned& klo,
                                             float& x, float& y, float& z) {
    unsigned khi2 = (unsigned)__builtin_amdgcn_update_dpp((int)khi, (int)khi, CTRL, 0xF, 0xF, false);
    unsigned klo2 = (unsigned)__builtin_amdgcn_update_dpp((int)klo, (int)klo, CTRL, 0xF, 0xF, false);
    int xi = __builtin_amdgcn_update_dpp(__float_as_int(x), __float_as_int(x), CTRL, 0xF, 0xF, false);
    int yi = __builtin_amdgcn_update_dpp(__float_as_int(y), __float_as_int(y), CTRL, 0xF, 0xF, false);
    int zi = __builtin_amdgcn_update_dpp(__float_as_int(z), __float_as_int(z), CTRL, 0xF, 0xF, false);
    unsigned long long k  = ((unsigned long long)khi  << 32) | klo;
    unsigned long long k2 = ((unsigned long long)khi2 << 32) | klo2;
    if (k2 > k) {
        khi = khi2; klo = klo2;
        x = __int_as_float(xi); y = __int_as_float(yi); z = __int_as_float(zi);
    }
}

// ---------------------------------------------------------------------------
// FPS: one workgroup per cloud, 512 threads (8 waves, 2/SIMD so dependent
// reduction chains of one wave overlap the dist loop of the other). pos in
// registers (8 pts/thr, static indexing only). Winner coords ride the
// reduction. Sampled indices buffered in LDS, dumped once at the end.
// Exact jnp semantics: d2 = ((dx*dx + dy*dy) + dz*dz) f32, no FMA contraction;
// argmax = first occurrence of max.
// ---------------------------------------------------------------------------
__global__ __launch_bounds__(TPB)
__attribute__((amdgpu_waves_per_eu(2)))
void fps_kernel(const float* __restrict__ pos, int* __restrict__ sidx) {
    __shared__ unsigned sw[2][NWAVE][8];   // [buf][wave] = {khi, klo, x, y, z}
    __shared__ int      sloc[M_SAMP];      // sampled local indices (4 KiB)

    const int cloud = blockIdx.x;
    const int tid   = threadIdx.x;
    const float* posb = pos + (size_t)cloud * N_PER * 3;

    // preload my 8 points straight from global (24 floats = 6 aligned float4)
    float px[PPT], py[PPT], pz[PPT], dist[PPT];
    {
        float f[24];
        const float4* posb4 = (const float4*)posb + tid * 6;
#pragma unroll
        for (int v = 0; v < 6; ++v) {
            float4 t = posb4[v];
            f[4 * v + 0] = t.x; f[4 * v + 1] = t.y;
            f[4 * v + 2] = t.z; f[4 * v + 3] = t.w;
        }
#pragma unroll
        for (int j = 0; j < PPT; ++j) {
            px[j] = f[3 * j]; py[j] = f[3 * j + 1]; pz[j] = f[3 * j + 2];
            dist[j] = 1e30f;
        }
    }
    const int base = tid * PPT;

    // current "last" point = local point 0 (deterministic start)
    float lx = posb[0], ly = posb[1], lz = posb[2];
    if (tid == 0) sloc[0] = 0;

    const int wave = tid >> 6;
    const int lane = tid & 63;

    for (int s = 1; s < M_SAMP; ++s) {
        // distance update + per-thread argmax carrying coords (all cndmask,
        // static register indices; ascending j + strict '>' => first occurrence)
        float bv = -1.0f;                 // all dist >= 0, so always beaten
        int   bi = 0;
        float cx = px[0], cy = py[0], cz = pz[0];
#pragma unroll
        for (int j = 0; j < PPT; ++j) {
            float dx = __fsub_rn(px[j], lx);
            float dy = __fsub_rn(py[j], ly);
            float dz = __fsub_rn(pz[j], lz);
            float d2 = __fadd_rn(__fadd_rn(__fmul_rn(dx, dx), __fmul_rn(dy, dy)),
                                 __fmul_rn(dz, dz));
            float dn = fminf(dist[j], d2);
            dist[j] = dn;
            bool t = dn > bv;
            bv = t ? dn : bv;
            bi = t ? j : bi;
            cx = t ? px[j] : cx;
            cy = t ? py[j] : cy;
            cz = t ? pz[j] : cz;
        }
        unsigned khi = __float_as_uint(bv);                  // bv >= 0: bits monotone
        unsigned klo = (unsigned)(N_PER - 1 - (base + bi));  // tie -> smaller idx wins

        // wave64 argmax via DPP (VALU-only, carries coords)
        dpp_combine5<0xB1>(khi, klo, cx, cy, cz);    // quad_perm xor1
        dpp_combine5<0x4E>(khi, klo, cx, cy, cz);    // quad_perm xor2
        dpp_combine5<0x141>(khi, klo, cx, cy, cz);   // row_half_mirror
        dpp_combine5<0x140>(khi, klo, cx, cy, cz);   // row_mirror
        dpp_combine5<0x142>(khi, klo, cx, cy, cz);   // row_bcast15
        dpp_combine5<0x143>(khi, klo, cx, cy, cz);   // row_bcast31
        // lane 63 holds the wave winner

        const int buf = s & 1;
        if (lane == 63) {
            sw[buf][wave][0] = khi; sw[buf][wave][1] = klo;
            sw[buf][wave][2] = __float_as_uint(cx);
            sw[buf][wave][3] = __float_as_uint(cy);
            sw[buf][wave][4] = __float_as_uint(cz);
        }
        __syncthreads();   // only LDS ops outstanding -> cheap lgkm drain

        // cross-wave merge: broadcast reads, unique keys -> exact winner
        unsigned wkhi = sw[buf][0][0], wklo = sw[buf][0][1];
        unsigned wx = sw[buf][0][2], wy = sw[buf][0][3], wz = sw[buf][0][4];
#pragma unroll
        for (int w = 1; w < NWAVE; ++w) {
            unsigned h2 = sw[buf][w][0], l2 = sw[buf][w][1];
            unsigned long long k  = ((unsigned long long)wkhi << 32) | wklo;
            unsigned long long k2 = ((unsigned long long)h2   << 32) | l2;
            if (k2 > k) {
                wkhi = h2; wklo = l2;
                wx = sw[buf][w][2]; wy = sw[buf][w][3]; wz = sw[buf][w][4];
            }
        }
        lx = __uint_as_float(wx); ly = __uint_as_float(wy); lz = __uint_as_float(wz);
        if (tid == 0) sloc[s] = N_PER - 1 - (int)wklo;   // LDS, drained next barrier
    }

    // dump sampled indices to global once (coalesced)
    __syncthreads();
    for (int i = tid; i < M_SAMP; i += TPB)
        sidx[cloud * M_SAMP + i] = sloc[i];
}

// ---------------------------------------------------------------------------
// Gather x rows: out[r][:] = x[g][:], float4-vectorized. 16384 rows x 128 f4.
// sidx holds LOCAL per-cloud indices; globalize with cloud offset r/M*N_PER.
// ---------------------------------------------------------------------------
__global__ __launch_bounds__(256) void gather_x_kernel(const float4* __restrict__ x4,
                                                       const int* __restrict__ sidx,
                                                       float4* __restrict__ out4) {
    int id = blockIdx.x * 256 + threadIdx.x;     // 0 .. 16384*128-1
    int r  = id >> 7;                            // row in output
    int c  = id & 127;                           // float4 column
    int g  = sidx[r] + (r >> 10 << 12);          // + (r/1024)*4096 global offset
    out4[id] = x4[(size_t)g * (D_FEAT / 4) + c];
}

// ---------------------------------------------------------------------------
// Gather pos (3 f32/row) and batch (as float). 16384 threads.
// ---------------------------------------------------------------------------
__global__ __launch_bounds__(256) void gather_pb_kernel(const float* __restrict__ pos,
                                                        const int* __restrict__ batch,
                                                        const int* __restrict__ sidx,
                                                        float* __restrict__ out_pos,
                                                        float* __restrict__ out_batch) {
    int r = blockIdx.x * 256 + threadIdx.x;      // 0 .. 16383
    int g = sidx[r] + (r >> 10 << 12);
    out_pos[r * 3 + 0] = pos[g * 3 + 0];
    out_pos[r * 3 + 1] = pos[g * 3 + 1];
    out_pos[r * 3 + 2] = pos[g * 3 + 2];
    out_batch[r] = (float)batch[g];
}

extern "C" void kernel_launch(void* const* d_in, const int* in_sizes, int n_in,
                              void* d_out, int out_size, void* d_ws, size_t ws_size,
                              hipStream_t stream) {
    const float* x     = (const float*)d_in[0];   // [65536,512] f32
    const float* pos   = (const float*)d_in[1];   // [65536,3]   f32
    const int*   batch = (const int*)d_in[2];     // [65536]     i32

    int* sidx = (int*)d_ws;                       // [16384] local sampled indices

    float* out   = (float*)d_out;
    float* out_x = out;                                            // 16384*512
    float* out_p = out + (size_t)B_CL * M_SAMP * D_FEAT;           // 16384*3
    float* out_b = out_p + (size_t)B_CL * M_SAMP * 3;              // 16384

    // 1) FPS: 16 blocks (one per cloud), 512 threads
    fps_kernel<<<B_CL, TPB, 0, stream>>>(pos, sidx);

    // 2) x gather: 16384 rows * 128 float4 / 256 threads = 8192 blocks
    gather_x_kernel<<<(B_CL * M_SAMP * (D_FEAT / 4)) / 256, 256, 0, stream>>>(
        (const float4*)x, sidx, (float4*)out_x);

    // 3) pos + batch gather: 16384 / 256 = 64 blocks
    gather_pb_kernel<<<(B_CL * M_SAMP) / 256, 256, 0, stream>>>(
        pos, batch, sidx, out_p, out_b);
}

// Round 6
// 750.131 us; speedup vs baseline: 1.8686x; 1.8686x over previous
//
#include <hip/hip_runtime.h>

// Problem constants (from reference): 16 clouds x 4096 pts, sample 1024, D=512
#define N_PER   4096
#define M_SAMP  1024
#define B_CL    16
#define D_FEAT  512
#define TPB     256
#define NWAVE   (TPB / 64)      // 4 waves
#define PPT     (N_PER / TPB)   // 16 points per thread
#define NPAIR   (PPT / 2)       // 8 packed pairs per thread

typedef float v2f __attribute__((ext_vector_type(2)));

// ---------------------------------------------------------------------------
// DPP u64-key argmax combine. key = (float_bits(val) << 32) | (4095 - idx):
//   max key == max val; tie -> min idx  (exact jnp.argmax first-occurrence).
// Lanes not supplied by the DPP pattern combine with themselves (no-op).
// ---------------------------------------------------------------------------
template <int CTRL>
__device__ __forceinline__ void dpp_combine2(unsigned& khi, unsigned& klo) {
    unsigned h2 = (unsigned)__builtin_amdgcn_update_dpp((int)khi, (int)khi, CTRL, 0xF, 0xF, false);
    unsigned l2 = (unsigned)__builtin_amdgcn_update_dpp((int)klo, (int)klo, CTRL, 0xF, 0xF, false);
    unsigned long long k  = ((unsigned long long)khi << 32) | klo;
    unsigned long long k2 = ((unsigned long long)h2  << 32) | l2;
    if (k2 > k) { khi = h2; klo = l2; }
}

// ---------------------------------------------------------------------------
// FPS: one workgroup per cloud, 256 threads. waves_per_eu(1,1): only 16 blocks
// exist chip-wide, so occupancy is worthless -- give each wave the full VGPR
// budget so px/py/pz/dist stay in real VGPRs (no AGPR shuttles).
// Dist update uses packed f32 (v_pk_*), contract(off) for exact jnp rounding:
//   d2 = ((dx*dx + dy*dy) + dz*dz), argmax = first occurrence of max.
// Reduction carries only a u64 key; winner coords looked up from LDS spos.
// ---------------------------------------------------------------------------
__global__ __launch_bounds__(TPB)
__attribute__((amdgpu_waves_per_eu(1, 1)))
void fps_kernel(const float* __restrict__ pos, int* __restrict__ sidx) {
    __shared__ float4             spos[N_PER];     // 64 KiB coord table
    __shared__ unsigned long long sw[2][NWAVE];    // double-buffered wave keys
    __shared__ int                sloc[M_SAMP];    // sampled local indices

    const int cloud = blockIdx.x;
    const int tid   = threadIdx.x;
    const float* posb = pos + (size_t)cloud * N_PER * 3;

    // preload my 16 points (12 aligned float4 from global), pack into v2f regs,
    // and stage the same points into spos (one-time; bank conflicts negligible)
    v2f px2[NPAIR], py2[NPAIR], pz2[NPAIR], dist2[NPAIR];
    const int base = tid * PPT;
    {
        float f[48];
        const float4* posb4 = (const float4*)posb + tid * 12;
#pragma unroll
        for (int v = 0; v < 12; ++v) {
            float4 t = posb4[v];
            f[4 * v + 0] = t.x; f[4 * v + 1] = t.y;
            f[4 * v + 2] = t.z; f[4 * v + 3] = t.w;
        }
#pragma unroll
        for (int p = 0; p < NPAIR; ++p) {
            px2[p] = (v2f){f[6 * p + 0], f[6 * p + 3]};
            py2[p] = (v2f){f[6 * p + 1], f[6 * p + 4]};
            pz2[p] = (v2f){f[6 * p + 2], f[6 * p + 5]};
            dist2[p] = (v2f){1e30f, 1e30f};
        }
#pragma unroll
        for (int j = 0; j < PPT; ++j)
            spos[base + j] = make_float4(f[3 * j], f[3 * j + 1], f[3 * j + 2], 0.0f);
    }

    float lx = posb[0], ly = posb[1], lz = posb[2];   // start point = local 0
    if (tid == 0) sloc[0] = 0;

    const int wave = tid >> 6;
    const int lane = tid & 63;
    __syncthreads();   // spos visible

    for (int s = 1; s < M_SAMP; ++s) {
        float bv = -1.0f;     // all dist >= 0, so always beaten
        int   bj = 0;
        v2f lxv = {lx, lx}, lyv = {ly, ly}, lzv = {lz, lz};
#pragma unroll
        for (int p = 0; p < NPAIR; ++p) {
#pragma clang fp contract(off)
            v2f dx = px2[p] - lxv;
            v2f dy = py2[p] - lyv;
            v2f dz = pz2[p] - lzv;
            v2f d2 = dx * dx + dy * dy + dz * dz;          // contract off: pk_mul+pk_add
            v2f dn = __builtin_elementwise_min(dist2[p], d2);
            dist2[p] = dn;
            // ascending index + strict '>' => first occurrence
            bool t0 = dn.x > bv; bv = t0 ? dn.x : bv; bj = t0 ? 2 * p     : bj;
            bool t1 = dn.y > bv; bv = t1 ? dn.y : bv; bj = t1 ? 2 * p + 1 : bj;
        }
        unsigned khi = __float_as_uint(bv);                 // bv >= 0: bits monotone
        unsigned klo = (unsigned)(N_PER - 1 - (base + bj)); // tie -> smaller idx wins

        // wave64 argmax via DPP (VALU-only, 2 regs)
        dpp_combine2<0xB1>(khi, klo);    // quad_perm xor1
        dpp_combine2<0x4E>(khi, klo);    // quad_perm xor2
        dpp_combine2<0x141>(khi, klo);   // row_half_mirror
        dpp_combine2<0x140>(khi, klo);   // row_mirror
        dpp_combine2<0x142>(khi, klo);   // row_bcast15
        dpp_combine2<0x143>(khi, klo);   // row_bcast31
        // lane 63 holds the wave winner

        const int buf = s & 1;
        if (lane == 63) sw[buf][wave] = ((unsigned long long)khi << 32) | klo;
        __syncthreads();   // only LDS outstanding -> cheap lgkm drain

        // cross-wave merge (broadcast b64 reads; keys unique -> exact winner)
        unsigned long long k = sw[buf][0];
#pragma unroll
        for (int w = 1; w < NWAVE; ++w) {
            unsigned long long k2 = sw[buf][w];
            if (k2 > k) k = k2;
        }
        int widx = N_PER - 1 - (int)(unsigned)(k & 0xFFFFFFFFu);
        float4 wp = spos[widx];            // broadcast ds_read_b128
        lx = wp.x; ly = wp.y; lz = wp.z;
        if (tid == 0) sloc[s] = widx;      // LDS, drained at next barrier
    }

    // dump sampled indices to global once (coalesced)
    __syncthreads();
    for (int i = tid; i < M_SAMP; i += TPB)
        sidx[cloud * M_SAMP + i] = sloc[i];
}

// ---------------------------------------------------------------------------
// Gather x rows: out[r][:] = x[g][:], float4-vectorized. 16384 rows x 128 f4.
// sidx holds LOCAL per-cloud indices; globalize with cloud offset r/M*N_PER.
// ---------------------------------------------------------------------------
__global__ __launch_bounds__(256) void gather_x_kernel(const float4* __restrict__ x4,
                                                       const int* __restrict__ sidx,
                                                       float4* __restrict__ out4) {
    int id = blockIdx.x * 256 + threadIdx.x;     // 0 .. 16384*128-1
    int r  = id >> 7;                            // row in output
    int c  = id & 127;                           // float4 column
    int g  = sidx[r] + (r >> 10 << 12);          // + (r/1024)*4096 global offset
    out4[id] = x4[(size_t)g * (D_FEAT / 4) + c];
}

// ---------------------------------------------------------------------------
// Gather pos (3 f32/row) and batch (as float). 16384 threads.
// ---------------------------------------------------------------------------
__global__ __launch_bounds__(256) void gather_pb_kernel(const float* __restrict__ pos,
                                                        const int* __restrict__ batch,
                                                        const int* __restrict__ sidx,
                                                        float* __restrict__ out_pos,
                                                        float* __restrict__ out_batch) {
    int r = blockIdx.x * 256 + threadIdx.x;      // 0 .. 16383
    int g = sidx[r] + (r >> 10 << 12);
    out_pos[r * 3 + 0] = pos[g * 3 + 0];
    out_pos[r * 3 + 1] = pos[g * 3 + 1];
    out_pos[r * 3 + 2] = pos[g * 3 + 2];
    out_batch[r] = (float)batch[g];
}

extern "C" void kernel_launch(void* const* d_in, const int* in_sizes, int n_in,
                              void* d_out, int out_size, void* d_ws, size_t ws_size,
                              hipStream_t stream) {
    const float* x     = (const float*)d_in[0];   // [65536,512] f32
    const float* pos   = (const float*)d_in[1];   // [65536,3]   f32
    const int*   batch = (const int*)d_in[2];     // [65536]     i32

    int* sidx = (int*)d_ws;                       // [16384] local sampled indices

    float* out   = (float*)d_out;
    float* out_x = out;                                            // 16384*512
    float* out_p = out + (size_t)B_CL * M_SAMP * D_FEAT;           // 16384*3
    float* out_b = out_p + (size_t)B_CL * M_SAMP * 3;              // 16384

    // 1) FPS: 16 blocks (one per cloud), 256 threads
    fps_kernel<<<B_CL, TPB, 0, stream>>>(pos, sidx);

    // 2) x gather: 16384 rows * 128 float4 / 256 threads = 8192 blocks
    gather_x_kernel<<<(B_CL * M_SAMP * (D_FEAT / 4)) / 256, 256, 0, stream>>>(
        (const float4*)x, sidx, (float4*)out_x);

    // 3) pos + batch gather: 16384 / 256 = 64 blocks
    gather_pb_kernel<<<(B_CL * M_SAMP) / 256, 256, 0, stream>>>(
        pos, batch, sidx, out_p, out_b);
}